// Round 6
// baseline (123.953 us; speedup 1.0000x reference)
//
#include <hip/hip_runtime.h>
#include <hip/hip_bf16.h>
#include <math.h>

// B=2, N=256, F=64, H=64, HEADS=4, C=256
#define EPSV 1e-5f
#define INFV 1e5f

typedef short bf16x8 __attribute__((ext_vector_type(8)));
typedef float f32x4 __attribute__((ext_vector_type(4)));

__device__ __forceinline__ float rcp_f(float x) { return __builtin_amdgcn_rcpf(x); }
__device__ __forceinline__ float silu_f(float v) { return v * rcp_f(1.0f + __expf(-v)); }

__device__ __forceinline__ unsigned short f2bf(float f) {
  unsigned int u = __float_as_uint(f);
  u = (u + 0x7fffu + ((u >> 16) & 1u)) >> 16;   // RNE
  return (unsigned short)u;
}
__device__ __forceinline__ float bf2f(unsigned short h) {
  return __uint_as_float(((unsigned int)h) << 16);
}
__device__ __forceinline__ unsigned int pkbf(float a, float b) {
  float2 f2; f2.x = a; f2.y = b;
  __hip_bfloat162 t = __float22bfloat162_rn(f2);
  unsigned int u;
  __builtin_memcpy(&u, &t, 4);
  return u;
}

// Block-wide float4 reduction over 512 threads where only waves 0-3 carry
// valid (non-duplicate) data. op=0 sum, op=1 max. All 512 must call.
__device__ __forceinline__ float4 br8(float4 v, int op, float4* sc) {
  const int tid = threadIdx.x;
#pragma unroll
  for (int off = 32; off >= 1; off >>= 1) {
    float ox = __shfl_xor(v.x, off);
    float oy = __shfl_xor(v.y, off);
    float oz = __shfl_xor(v.z, off);
    float ow = __shfl_xor(v.w, off);
    if (op) { v.x = fmaxf(v.x, ox); v.y = fmaxf(v.y, oy); v.z = fmaxf(v.z, oz); v.w = fmaxf(v.w, ow); }
    else    { v.x += ox; v.y += oy; v.z += oz; v.w += ow; }
  }
  if ((tid & 63) == 0 && (tid >> 6) < 4) sc[tid >> 6] = v;
  __syncthreads();
  float4 r0 = sc[0], r1 = sc[1], r2 = sc[2], r3 = sc[3];
  if (op) {
    v.x = fmaxf(fmaxf(r0.x, r1.x), fmaxf(r2.x, r3.x));
    v.y = fmaxf(fmaxf(r0.y, r1.y), fmaxf(r2.y, r3.y));
    v.z = fmaxf(fmaxf(r0.z, r1.z), fmaxf(r2.z, r3.z));
    v.w = fmaxf(fmaxf(r0.w, r1.w), fmaxf(r2.w, r3.w));
  } else {
    v.x = r0.x + r1.x + r2.x + r3.x;
    v.y = r0.y + r1.y + r2.y + r3.y;
    v.z = r0.z + r1.z + r2.z + r3.z;
    v.w = r0.w + r1.w + r2.w + r3.w;
  }
  __syncthreads();
  return v;
}

// One block per (b,i), 512 threads (8 waves). All 512 blocks co-resident
// (2 blocks/CU): duration == single-block critical path, so per-thread work
// is halved vs the 256-thread version.
__global__ __launch_bounds__(512, 4) void k_all(
    const float* __restrict__ h, const float* __restrict__ x, const float* __restrict__ v,
    const float* __restrict__ ew1, const float* __restrict__ eb1,
    const float* __restrict__ ew2, const float* __restrict__ eb2,
    const float* __restrict__ semw, const float* __restrict__ semb,
    const float* __restrict__ pw1, const float* __restrict__ pb1,
    const float* __restrict__ pw2, const float* __restrict__ pb2,
    const float* __restrict__ nw1, const float* __restrict__ nb1,
    const float* __restrict__ nw2, const float* __restrict__ nb2,
    const float* __restrict__ vw1, const float* __restrict__ vb1,
    const float* __restrict__ vw2, const float* __restrict__ vmix,
    const float* __restrict__ lgam, float* __restrict__ out) {

  __shared__ __align__(16) unsigned short TH[256 * 72];   // HB -> T -> HE ; then tail scratch
  __shared__ __align__(16) char E2u[9216];                // E2T / sd / cat+cn+hag / sc
  __shared__ __align__(16) float4 unit_l[256];            // .xyz unit, .w dn
  __shared__ __align__(16) float bms[512];
  __shared__ __align__(16) float addk[64];
  __shared__ __align__(16) float w1dk[64];

  unsigned short* E2T = (unsigned short*)E2u;
  float*  sd    = (float*)E2u;               // [256*8]
  float4* cat_l = (float4*)E2u;              // [256] (overlays sd after it's consumed)
  float*  cn_l  = (float*)(E2u + 4096);      // [256]
  float*  hag_l = (float*)(E2u + 5120);      // [256]
  float4* sc    = (float4*)(E2u + 8192);     // [8]
  // tail scratch overlaid on TH (dead after P4)
  float* tmp = (float*)TH;                   // [512]
  float* m1s = (float*)TH + 512;             // [64]
  float* hnw = (float*)TH + 576;             // [64]
  float* nin = (float*)TH + 640;             // [384]

  const int bi  = blockIdx.x;
  const int i   = bi & 255;
  const int b0  = bi & ~255;
  const int tid = threadIdx.x;
  const int w    = tid >> 6;
  const int lid  = tid & 63;
  const int l15  = lid & 15;
  const int quad = lid >> 4;
  const int j8   = tid & 255;       // waves 4-7 duplicate waves 0-3 for per-j phases
  const int bj   = b0 | j8;

  // ================= P0: geometry + staging =================
  const float xi0 = x[bi * 3 + 0], xi1 = x[bi * 3 + 1], xi2 = x[bi * 3 + 2];
  const float dx = x[bj * 3 + 0] - xi0;
  const float dy = x[bj * 3 + 1] - xi1;
  const float dz = x[bj * 3 + 2] - xi2;
  const float dn = sqrtf(dx * dx + dy * dy + dz * dz + EPSV);
  const float invn = rcp_f(dn + EPSV);
  const float ux = dx * invn, uy = dy * invn, uz = dz * invn;
  unit_l[j8] = make_float4(ux, uy, uz, dn);   // duplicate identical write is benign

  {
    const float4* hb4 = reinterpret_cast<const float4*>(h + (size_t)b0 * 64);
#pragma unroll
    for (int q = 0; q < 8; ++q) {
      int idx = q * 512 + tid;            // 0..4095 float4s
      float4 f4 = hb4[idx];
      int row = idx >> 4, c4 = idx & 15;
      uint2 pk;
      pk.x = pkbf(f4.x, f4.y);
      pk.y = pkbf(f4.z, f4.w);
      *reinterpret_cast<uint2*>(&TH[row * 72 + c4 * 4]) = pk;
    }
  }
  // stage W1a^T
#pragma unroll
  for (int q = 0; q < 8; ++q) {
    int idx = q * 512 + tid;              // f*64+k
    E2T[(idx & 63) * 72 + (idx >> 6)] = f2bf(ew1[idx]);
  }
  // Bm_i partials (fp32 exact), 8 strips of 8 f
  {
    int s = tid >> 6, k0 = tid & 63;
    const float* hrow = h + (size_t)bi * 64;      // uniform -> scalar loads
    float bp = 0.f;
#pragma unroll
    for (int f2 = 0; f2 < 8; ++f2) {
      int f = s * 8 + f2;
      bp += hrow[f] * ew1[(64 + f) * 64 + k0];
    }
    bms[s * 64 + k0] = bp;
  }
  __syncthreads();                                               // s1
  if (tid < 64) {
    float a = eb1[tid];
#pragma unroll
    for (int s2 = 0; s2 < 8; ++s2) a += bms[s2 * 64 + tid];
    addk[tid] = a;
    w1dk[tid] = ew1[128 * 64 + tid];
  }

  // ================= P1: GEMM1' = W1a^T @ HB^T (output T^T, M=k_out, N=j) =====
  // Wave w owns n = j in [32w, 32w+32): 4 m-tiles x 2 n-tiles.
  f32x4 acc1[4][2];
#pragma unroll
  for (int tm = 0; tm < 4; ++tm)
#pragma unroll
    for (int tn = 0; tn < 2; ++tn) acc1[tm][tn] = (f32x4){0.f, 0.f, 0.f, 0.f};
#pragma unroll
  for (int ms = 0; ms < 64; ms += 32) {
    bf16x8 am[4], bn[2];
#pragma unroll
    for (int tm = 0; tm < 4; ++tm)
      am[tm] = *reinterpret_cast<const bf16x8*>(&E2T[(16 * tm + l15) * 72 + ms + quad * 8]);
#pragma unroll
    for (int tn = 0; tn < 2; ++tn)
      bn[tn] = *reinterpret_cast<const bf16x8*>(&TH[(32 * w + 16 * tn + l15) * 72 + ms + quad * 8]);
#pragma unroll
    for (int tm = 0; tm < 4; ++tm)
#pragma unroll
      for (int tn = 0; tn < 2; ++tn)
        acc1[tm][tn] = __builtin_amdgcn_mfma_f32_16x16x32_bf16(am[tm], bn[tn], acc1[tm][tn], 0, 0, 0);
  }
  __syncthreads();   // s2: addk visible; E2T (W1a) reads done; HB frag reads done

  // epilogue1: T[j][k] = silu(acc + addk[k] + dn[j]*w1d[k]); b64-packed writes (own rows)
#pragma unroll
  for (int tn = 0; tn < 2; ++tn) {
    int j = 32 * w + 16 * tn + l15;
    float dnj = unit_l[j].w;
#pragma unroll
    for (int tm = 0; tm < 4; ++tm) {
      float4 ad = *reinterpret_cast<const float4*>(&addk[16 * tm + 4 * quad]);
      float4 wd = *reinterpret_cast<const float4*>(&w1dk[16 * tm + 4 * quad]);
      float v0 = silu_f(acc1[tm][tn][0] + ad.x + dnj * wd.x);
      float v1 = silu_f(acc1[tm][tn][1] + ad.y + dnj * wd.y);
      float v2 = silu_f(acc1[tm][tn][2] + ad.z + dnj * wd.z);
      float v3 = silu_f(acc1[tm][tn][3] + ad.w + dnj * wd.w);
      uint2 pk;
      pk.x = pkbf(v0, v1);
      pk.y = pkbf(v2, v3);
      *reinterpret_cast<uint2*>(&TH[j * 72 + 16 * tm + 4 * quad]) = pk;
    }
  }
  // restage W2^T
#pragma unroll
  for (int q = 0; q < 8; ++q) {
    int idx = q * 512 + tid;
    E2T[(idx & 63) * 72 + (idx >> 6)] = f2bf(ew2[idx]);
  }
  __syncthreads();                                               // s3

  // ================= P2: GEMM2 (HE = T @ W2), wave rows [32w, 32w+32) =========
  f32x4 acc2[2][4];
#pragma unroll
  for (int tr = 0; tr < 2; ++tr)
#pragma unroll
    for (int tc = 0; tc < 4; ++tc) acc2[tr][tc] = (f32x4){0.f, 0.f, 0.f, 0.f};
#pragma unroll
  for (int ms = 0; ms < 64; ms += 32) {
    bf16x8 af[2], bfr[4];
#pragma unroll
    for (int tr = 0; tr < 2; ++tr)
      af[tr] = *reinterpret_cast<const bf16x8*>(&TH[(32 * w + 16 * tr + l15) * 72 + ms + quad * 8]);
#pragma unroll
    for (int tc = 0; tc < 4; ++tc)
      bfr[tc] = *reinterpret_cast<const bf16x8*>(&E2T[(16 * tc + l15) * 72 + ms + quad * 8]);
#pragma unroll
    for (int tr = 0; tr < 2; ++tr)
#pragma unroll
      for (int tc = 0; tc < 4; ++tc)
        acc2[tr][tc] = __builtin_amdgcn_mfma_f32_16x16x32_bf16(af[tr], bfr[tc], acc2[tr][tc], 0, 0, 0);
  }
  __syncthreads();   // s4: W2 frag reads done (allows Wsv restage)

  // epilogue2: HE = silu(. + eb2) -> TH (own rows) ; restage E3T = [semw|vmix]^T
#pragma unroll
  for (int tc = 0; tc < 4; ++tc) {
    float b2 = eb2[16 * tc + l15];
#pragma unroll
    for (int tr = 0; tr < 2; ++tr)
#pragma unroll
      for (int r = 0; r < 4; ++r) {
        int row = 32 * w + 16 * tr + quad * 4 + r;
        TH[row * 72 + 16 * tc + l15] = f2bf(silu_f(acc2[tr][tc][r] + b2));
      }
  }
  {
    int n = tid >> 6, kk = tid & 63;      // 512 = 8 rows x 64
    float wv = (n < 4) ? semw[kk * 4 + n] : vmix[kk * 4 + (n - 4)];
    E2T[n * 72 + kk] = f2bf(wv);
  }
  __syncthreads();                                               // s5

  // ================= P2b: GEMM3 (HE @ [semw|vmix]) =================
  f32x4 acc3[2];
  acc3[0] = (f32x4){0.f, 0.f, 0.f, 0.f};
  acc3[1] = (f32x4){0.f, 0.f, 0.f, 0.f};
#pragma unroll
  for (int ms = 0; ms < 64; ms += 32) {
    bf16x8 b3 = *reinterpret_cast<const bf16x8*>(&E2T[l15 * 72 + ms + quad * 8]);
#pragma unroll
    for (int tr = 0; tr < 2; ++tr) {
      bf16x8 a3 = *reinterpret_cast<const bf16x8*>(&TH[(32 * w + 16 * tr + l15) * 72 + ms + quad * 8]);
      acc3[tr] = __builtin_amdgcn_mfma_f32_16x16x32_bf16(a3, b3, acc3[tr], 0, 0, 0);
    }
  }
  __syncthreads();   // s6: Wsv frag reads done before sd overwrite of E2u
  if (l15 < 8) {
#pragma unroll
    for (int tr = 0; tr < 2; ++tr)
#pragma unroll
      for (int r = 0; r < 4; ++r)
        sd[(32 * w + 16 * tr + quad * 4 + r) * 8 + l15] = acc3[tr][r];
  }
  __syncthreads();                                               // s7

  // ================= P3: attentions (thread -> j8, waves 4-7 duplicate) =======
  float dv0 = 0.f, dv1 = 0.f, dv2 = 0.f;
  {
    float4 s01 = *reinterpret_cast<const float4*>(sd + j8 * 8);
    float4 s23 = *reinterpret_cast<const float4*>(sd + j8 * 8 + 4);
    float4 sbv = *reinterpret_cast<const float4*>(semb);
    const float diag = (j8 == i) ? INFV : 0.0f;
    float4 sl;
    sl.x = s01.x + sbv.x; sl.y = s01.y + sbv.y; sl.z = s01.z + sbv.z; sl.w = s01.w + sbv.w;
    sl.x = ((sl.x > 0.f) ? sl.x : 0.2f * sl.x) - diag;
    sl.y = ((sl.y > 0.f) ? sl.y : 0.2f * sl.y) - diag;
    sl.z = ((sl.z > 0.f) ? sl.z : 0.2f * sl.z) - diag;
    sl.w = ((sl.w > 0.f) ? sl.w : 0.2f * sl.w) - diag;

    float4 lg = *reinterpret_cast<const float4*>(lgam);
    const float dni = dn + diag;
    float4 e_eu = make_float4(__expf(-dni * __expf(lg.x)), __expf(-dni * __expf(lg.y)),
                              __expf(-dni * __expf(lg.z)), __expf(-dni * __expf(lg.w)));

    float4 M = br8(sl, 1, sc);   // sd reads of ALL threads complete at this sync
    float4 e_sem = make_float4(__expf(sl.x - M.x), __expf(sl.y - M.y),
                               __expf(sl.z - M.z), __expf(sl.w - M.w));

    // batched sums of e_eu and e_sem
    float4 a8 = e_eu, b8 = e_sem;
#pragma unroll
    for (int off = 32; off >= 1; off >>= 1) {
      a8.x += __shfl_xor(a8.x, off); a8.y += __shfl_xor(a8.y, off);
      a8.z += __shfl_xor(a8.z, off); a8.w += __shfl_xor(a8.w, off);
      b8.x += __shfl_xor(b8.x, off); b8.y += __shfl_xor(b8.y, off);
      b8.z += __shfl_xor(b8.z, off); b8.w += __shfl_xor(b8.w, off);
    }
    if ((tid & 63) == 0 && w < 4) { sc[w] = a8; sc[4 + w] = b8; }
    __syncthreads();
    float4 Se, Ss;
    {
      float4 r0 = sc[0], r1 = sc[1], r2 = sc[2], r3 = sc[3];
      Se = make_float4(r0.x + r1.x + r2.x + r3.x, r0.y + r1.y + r2.y + r3.y,
                       r0.z + r1.z + r2.z + r3.z, r0.w + r1.w + r2.w + r3.w);
      float4 s0 = sc[4], s1 = sc[5], s2 = sc[6], s3 = sc[7];
      Ss = make_float4(s0.x + s1.x + s2.x + s3.x, s0.y + s1.y + s2.y + s3.y,
                       s0.z + s1.z + s2.z + s3.z, s0.w + s1.w + s2.w + s3.w);
    }
    __syncthreads();

    float4 p = make_float4((e_eu.x * rcp_f(Se.x)) * (e_sem.x * rcp_f(Ss.x)),
                           (e_eu.y * rcp_f(Se.y)) * (e_sem.y * rcp_f(Ss.y)),
                           (e_eu.z * rcp_f(Se.z)) * (e_sem.z * rcp_f(Ss.z)),
                           (e_eu.w * rcp_f(Se.w)) * (e_sem.w * rcp_f(Ss.w)));
    float4 ep = make_float4(__expf(p.x), __expf(p.y), __expf(p.z), __expf(p.w));
    float4 Sp = br8(ep, 0, sc);
    float4 catt = make_float4(ep.x * rcp_f(Sp.x), ep.y * rcp_f(Sp.y),
                              ep.z * rcp_f(Sp.z), ep.w * rcp_f(Sp.w));
    cat_l[j8] = catt;   // overlays sd (consumed); duplicate write identical

    float s = catt.x * s23.x + catt.y * s23.y + catt.z * s23.z + catt.w * s23.w;
    float4 dv = br8(make_float4(s * ux, s * uy, s * uz, 0.f), 0, sc);
    const float inv = 1.0f / 256.0f;
    dv0 = dv.x * inv; dv1 = dv.y * inv; dv2 = dv.z * inv;   // valid in all threads
  }
  // last br8 ended with a sync: cat_l visible to all

  // ========== P4: comb_sum / h_agg. wave w -> k in [8w,8w+8), conflict-free ====
  {
    const int g  = lid >> 3;        // k = 8w + g
    const int jq = lid & 7;         // j group [32jq, 32jq+32)
    const int k  = 8 * w + g;
    float agg[4] = {0.f, 0.f, 0.f, 0.f};
    float ax[4]  = {0.f, 0.f, 0.f, 0.f};
    float ay[4]  = {0.f, 0.f, 0.f, 0.f};
    float az[4]  = {0.f, 0.f, 0.f, 0.f};
#pragma unroll 4
    for (int it = 0; it < 32; ++it) {
      int jj = 32 * jq + ((it + jq) & 31);   // bank-disjoint across jq
      float hev = bf2f(TH[jj * 72 + k]);
      float4 ca = cat_l[jj];
      float4 u  = unit_l[jj];
      float w0 = hev * ca.x, w1 = hev * ca.y, w2 = hev * ca.z, w3 = hev * ca.w;
      agg[0] += w0; agg[1] += w1; agg[2] += w2; agg[3] += w3;
      ax[0] += w0 * u.x; ay[0] += w0 * u.y; az[0] += w0 * u.z;
      ax[1] += w1 * u.x; ay[1] += w1 * u.y; az[1] += w1 * u.z;
      ax[2] += w2 * u.x; ay[2] += w2 * u.y; az[2] += w2 * u.z;
      ax[3] += w3 * u.x; ay[3] += w3 * u.y; az[3] += w3 * u.z;
    }
    // reduce over jq (lane bits 0..2)
#pragma unroll
    for (int off = 1; off <= 4; off <<= 1) {
#pragma unroll
      for (int hd = 0; hd < 4; ++hd) {
        agg[hd] += __shfl_xor(agg[hd], off);
        ax[hd]  += __shfl_xor(ax[hd], off);
        ay[hd]  += __shfl_xor(ay[hd], off);
        az[hd]  += __shfl_xor(az[hd], off);
      }
    }
    if (jq == 0) {
      const float inv = 1.0f / 256.0f;
#pragma unroll
      for (int hd = 0; hd < 4; ++hd) {
        float cx = ax[hd] * inv, cy = ay[hd] * inv, cz = az[hd] * inv;
        cn_l[k * 4 + hd]  = cx * cx + cy * cy + cz * cz;
        hag_l[k * 4 + hd] = agg[hd];
      }
    }
  }
  __syncthreads();                                               // s8: TH free

  // ================= P5: tail MLPs, 8-strip parallel =================
  const int k0 = tid & 63;
  // post1: 256 -> 64 (strips of 32)
  {
    float a = 0.f;
    for (int m2 = 0; m2 < 32; ++m2) {
      int m = w * 32 + m2;
      a += cn_l[m] * pw1[m * 64 + k0];
    }
    tmp[tid] = a;
  }
  __syncthreads();
  if (tid < 64) {
    float a = pb1[tid];
#pragma unroll
    for (int s2 = 0; s2 < 8; ++s2) a += tmp[tid + 64 * s2];
    m1s[tid] = silu_f(a);
  }
  __syncthreads();
  // post2: 64 -> 64 (strips of 8); also stage h_agg into nin
  {
    float a = 0.f;
#pragma unroll
    for (int m2 = 0; m2 < 8; ++m2) {
      int m = w * 8 + m2;
      a += m1s[m] * pw2[m * 64 + k0];
    }
    float hgv = hag_l[j8];
    __syncthreads();            // m1s reads done before tmp overwrite? (tmp!=m1s, but keep ordering cheap)
    tmp[tid] = a;
    nin[64 + j8] = hgv;         // duplicate identical write
  }
  __syncthreads();
  if (tid < 64) {
    float a = pb2[tid];
#pragma unroll
    for (int s2 = 0; s2 < 8; ++s2) a += tmp[tid + 64 * s2];
    nin[tid] = h[(size_t)bi * 64 + tid];
    nin[320 + tid] = silu_f(a);
  }
  __syncthreads();
  // node1: 384 -> 64 (strips of 48)
  {
    float a = 0.f;
    for (int m2 = 0; m2 < 48; ++m2) {
      int m = w * 48 + m2;
      a += nin[m] * nw1[m * 64 + k0];
    }
    __syncthreads();
    tmp[tid] = a;
  }
  __syncthreads();
  if (tid < 64) {
    float a = nb1[tid];
#pragma unroll
    for (int s2 = 0; s2 < 8; ++s2) a += tmp[tid + 64 * s2];
    m1s[tid] = silu_f(a);
  }
  __syncthreads();
  // node2: 64 -> 64, residual
  {
    float a = 0.f;
#pragma unroll
    for (int m2 = 0; m2 < 8; ++m2) {
      int m = w * 8 + m2;
      a += m1s[m] * nw2[m * 64 + k0];
    }
    __syncthreads();
    tmp[tid] = a;
  }
  __syncthreads();
  if (tid < 64) {
    float a = nb2[tid];
#pragma unroll
    for (int s2 = 0; s2 < 8; ++s2) a += tmp[tid + 64 * s2];
    float hn = h[(size_t)bi * 64 + tid] + silu_f(a);
    out[(size_t)bi * 64 + tid] = hn;
    hnw[tid] = hn;
  }
  __syncthreads();
  // vel: 64 -> 64 -> scalar, then x/v outputs
  {
    float a = 0.f;
#pragma unroll
    for (int m2 = 0; m2 < 8; ++m2) {
      int m = w * 8 + m2;
      a += hnw[m] * vw1[m * 64 + k0];
    }
    __syncthreads();
    tmp[tid] = a;
  }
  __syncthreads();
  if (tid < 64) {
    float a = vb1[tid];
#pragma unroll
    for (int s2 = 0; s2 < 8; ++s2) a += tmp[tid + 64 * s2];
    float vh = silu_f(a) * vw2[tid];
#pragma unroll
    for (int off = 32; off >= 1; off >>= 1) vh += __shfl_xor(vh, off);
    if (tid == 0) {
      float dvv[3] = {dv0, dv1, dv2};
#pragma unroll
      for (int d = 0; d < 3; ++d) {
        float vn = dvv[d] + vh * v[bi * 3 + d];
        out[32768 + bi * 3 + d] = x[bi * 3 + d] + vn;
        out[34304 + bi * 3 + d] = vn;
      }
    }
  }
}

extern "C" void kernel_launch(void* const* d_in, const int* in_sizes, int n_in,
                              void* d_out, int out_size, void* d_ws, size_t ws_size,
                              hipStream_t stream) {
  const float* h    = (const float*)d_in[0];
  const float* x    = (const float*)d_in[1];
  const float* v    = (const float*)d_in[2];
  const float* ew1  = (const float*)d_in[3];
  const float* eb1  = (const float*)d_in[4];
  const float* ew2  = (const float*)d_in[5];
  const float* eb2  = (const float*)d_in[6];
  const float* semw = (const float*)d_in[7];
  const float* semb = (const float*)d_in[8];
  const float* pw1  = (const float*)d_in[9];
  const float* pb1  = (const float*)d_in[10];
  const float* pw2  = (const float*)d_in[11];
  const float* pb2  = (const float*)d_in[12];
  const float* nw1  = (const float*)d_in[13];
  const float* nb1  = (const float*)d_in[14];
  const float* nw2  = (const float*)d_in[15];
  const float* nb2  = (const float*)d_in[16];
  const float* vw1  = (const float*)d_in[17];
  const float* vb1  = (const float*)d_in[18];
  const float* vw2  = (const float*)d_in[19];
  const float* vmix = (const float*)d_in[20];
  const float* lgam = (const float*)d_in[21];
  float* out = (float*)d_out;

  k_all<<<512, 512, 0, stream>>>(h, x, v, ew1, eb1, ew2, eb2, semw, semb,
                                 pw1, pb1, pw2, pb2, nw1, nb1, nw2, nb2,
                                 vw1, vb1, vw2, vmix, lgam, out);
}

// Round 7
// 122.593 us; speedup vs baseline: 1.0111x; 1.0111x over previous
//
#include <hip/hip_runtime.h>
#include <hip/hip_bf16.h>
#include <math.h>

// B=2, N=256, F=64, H=64, HEADS=4, C=256
#define EPSV 1e-5f
#define INFV 1e5f

typedef short bf16x8 __attribute__((ext_vector_type(8)));
typedef float f32x4 __attribute__((ext_vector_type(4)));

__device__ __forceinline__ float rcp_f(float x) { return __builtin_amdgcn_rcpf(x); }
__device__ __forceinline__ float silu_f(float v) { return v * rcp_f(1.0f + __expf(-v)); }

__device__ __forceinline__ unsigned short f2bf(float f) {
  unsigned int u = __float_as_uint(f);
  u = (u + 0x7fffu + ((u >> 16) & 1u)) >> 16;   // RNE
  return (unsigned short)u;
}
__device__ __forceinline__ float bf2f(unsigned short h) {
  return __uint_as_float(((unsigned int)h) << 16);
}
__device__ __forceinline__ unsigned int pkbf(float a, float b) {
  float2 f2; f2.x = a; f2.y = b;
  __hip_bfloat162 t = __float22bfloat162_rn(f2);
  unsigned int u;
  __builtin_memcpy(&u, &t, 4);
  return u;
}

// 64x64 @ 64x64 GEMM (GEMM1): A rows from TH (stride 72 u16), B from E2T (stride 72).
__device__ __forceinline__ void gemm64(const unsigned short* TH, const unsigned short* E2T,
                                       int w, int l15, int quad, f32x4 acc[4][4]) {
#pragma unroll
  for (int tr = 0; tr < 4; ++tr)
#pragma unroll
    for (int tc = 0; tc < 4; ++tc)
      acc[tr][tc] = (f32x4){0.f, 0.f, 0.f, 0.f};
#pragma unroll
  for (int ms = 0; ms < 64; ms += 32) {
    bf16x8 af[4], bfr[4];
#pragma unroll
    for (int tr = 0; tr < 4; ++tr)
      af[tr] = *reinterpret_cast<const bf16x8*>(&TH[(64 * w + 16 * tr + l15) * 72 + ms + quad * 8]);
#pragma unroll
    for (int tc = 0; tc < 4; ++tc)
      bfr[tc] = *reinterpret_cast<const bf16x8*>(&E2T[(16 * tc + l15) * 72 + ms + quad * 8]);
#pragma unroll
    for (int tr = 0; tr < 4; ++tr)
#pragma unroll
      for (int tc = 0; tc < 4; ++tc)
        acc[tr][tc] = __builtin_amdgcn_mfma_f32_16x16x32_bf16(af[tr], bfr[tc], acc[tr][tc], 0, 0, 0);
  }
}

// One block per (b,i), 256 threads (4 waves). Grid 512 = 2 blocks/CU co-resident.
__global__ __launch_bounds__(256, 2) void k_all(
    const float* __restrict__ h, const float* __restrict__ x, const float* __restrict__ v,
    const float* __restrict__ ew1, const float* __restrict__ eb1,
    const float* __restrict__ ew2, const float* __restrict__ eb2,
    const float* __restrict__ semw, const float* __restrict__ semb,
    const float* __restrict__ pw1, const float* __restrict__ pb1,
    const float* __restrict__ pw2, const float* __restrict__ pb2,
    const float* __restrict__ nw1, const float* __restrict__ nb1,
    const float* __restrict__ nw2, const float* __restrict__ nb2,
    const float* __restrict__ vw1, const float* __restrict__ vb1,
    const float* __restrict__ vw2, const float* __restrict__ vmix,
    const float* __restrict__ lgam, float* __restrict__ out) {

  // THu: HB/T rows (stride 72) -> HEt[64ch][264 j] (stride 264, 16B-aligned) -> tail scratch
  __shared__ __align__(16) unsigned short THu[256 * 72];    // 36864 B
  // E2u: W1a^T / W2^T (stride 72) -> Bt[16][264]
  __shared__ __align__(16) unsigned short E2u[64 * 72];     // 9216 B
  __shared__ __align__(16) float dn_l[256];
  __shared__ __align__(16) float comps[64 * 12];            // comb_sum components
  __shared__ __align__(16) float cn_l[256];
  __shared__ __align__(16) float hag_l[256];
  __shared__ __align__(16) float bms[256];
  __shared__ __align__(16) float addk[64];
  __shared__ __align__(16) float w1dk[64];
  __shared__ __align__(16) float4 sc[8];

  unsigned short* TH  = THu;
  unsigned short* HEt = THu;     // 64 x 264 u16, overlays TH after GEMM2 (hoist+barrier)
  unsigned short* E2T = E2u;
  unsigned short* Bt  = E2u;     // 16 x 264 u16, overlays W2 stage after P3
  float* tmp = (float*)THu;      // tail scratch (HEt dead after P4)
  float* m1s = (float*)THu + 256;
  float* hnw = (float*)THu + 320;
  float* nin = (float*)THu + 384;

  const int bi  = blockIdx.x;
  const int i   = bi & 255;
  const int b0  = bi & ~255;
  const int tid = threadIdx.x;
  const int j   = tid;
  const int bj  = b0 | j;
  const int w    = tid >> 6;
  const int lid  = tid & 63;
  const int l15  = lid & 15;
  const int quad = lid >> 4;

  // ================= P0: geometry + staging =================
  const float xi0 = x[bi * 3 + 0], xi1 = x[bi * 3 + 1], xi2 = x[bi * 3 + 2];
  const float dx = x[bj * 3 + 0] - xi0;
  const float dy = x[bj * 3 + 1] - xi1;
  const float dz = x[bj * 3 + 2] - xi2;
  const float dn = sqrtf(dx * dx + dy * dy + dz * dz + EPSV);
  const float invn = rcp_f(dn + EPSV);
  const float ux = dx * invn, uy = dy * invn, uz = dz * invn;
  dn_l[j] = dn;

  {
    const float4* hb4 = reinterpret_cast<const float4*>(h + (size_t)b0 * 64);
#pragma unroll
    for (int q = 0; q < 16; ++q) {
      int idx = q * 256 + tid;            // 0..4095 float4s
      float4 f4 = hb4[idx];
      int row = idx >> 4, c4 = idx & 15;
      uint2 pk;
      pk.x = pkbf(f4.x, f4.y);
      pk.y = pkbf(f4.z, f4.w);
      *reinterpret_cast<uint2*>(&TH[row * 72 + c4 * 4]) = pk;
    }
  }
  // stage W1a^T
#pragma unroll
  for (int q = 0; q < 16; ++q) {
    int idx = q * 256 + tid;              // f*64+k
    E2T[(idx & 63) * 72 + (idx >> 6)] = f2bf(ew1[idx]);
  }
  // Bm_i partials (fp32 exact)
  {
    int s = tid >> 6, k = tid & 63;
    const float* hrow = h + (size_t)bi * 64;      // uniform -> scalar loads
    float bp = 0.f;
#pragma unroll
    for (int f2 = 0; f2 < 16; ++f2) {
      int f = s * 16 + f2;
      bp += hrow[f] * ew1[(64 + f) * 64 + k];
    }
    bms[s * 64 + k] = bp;
  }
  __syncthreads();                                               // s1
  if (tid < 64) {
    addk[tid] = eb1[tid] + bms[tid] + bms[64 + tid] + bms[128 + tid] + bms[192 + tid];
    w1dk[tid] = ew1[128 * 64 + tid];
  }

  // ================= P1: GEMM1 (h_b @ W1a) =================
  f32x4 acc[4][4];
  gemm64(TH, E2T, w, l15, quad, acc);
  __syncthreads();                                               // s2

  // epilogue1: T = silu(A + Bm_i + dn*w1d + eb1) -> TH (own rows, no cross-wave alias)
#pragma unroll
  for (int tc = 0; tc < 4; ++tc) {
    float ak = addk[16 * tc + l15];
    float wd = w1dk[16 * tc + l15];
#pragma unroll
    for (int tr = 0; tr < 4; ++tr)
#pragma unroll
      for (int r = 0; r < 4; ++r) {
        int row = 64 * w + 16 * tr + quad * 4 + r;
        float val = silu_f(acc[tr][tc][r] + ak + dn_l[row] * wd);
        TH[row * 72 + 16 * tc + l15] = f2bf(val);
      }
  }
  // restage W2^T
#pragma unroll
  for (int q = 0; q < 16; ++q) {
    int idx = q * 256 + tid;
    E2T[(idx & 63) * 72 + (idx >> 6)] = f2bf(ew2[idx]);
  }
  __syncthreads();                                               // s3

  // ========= P2: GEMM2 (HE = T @ W2) with HOISTED fragments, output -> HEt =========
  {
    bf16x8 a2[4][2], b2[4][2];
#pragma unroll
    for (int tr = 0; tr < 4; ++tr)
#pragma unroll
      for (int ms = 0; ms < 2; ++ms)
        a2[tr][ms] = *reinterpret_cast<const bf16x8*>(&TH[(64 * w + 16 * tr + l15) * 72 + ms * 32 + quad * 8]);
#pragma unroll
    for (int tc = 0; tc < 4; ++tc)
#pragma unroll
      for (int ms = 0; ms < 2; ++ms)
        b2[tc][ms] = *reinterpret_cast<const bf16x8*>(&E2T[(16 * tc + l15) * 72 + ms * 32 + quad * 8]);
    __syncthreads();   // s4: every wave's T + W2 reads complete -> safe to overwrite THu
#pragma unroll
    for (int tr = 0; tr < 4; ++tr)
#pragma unroll
      for (int tc = 0; tc < 4; ++tc)
        acc[tr][tc] = (f32x4){0.f, 0.f, 0.f, 0.f};
#pragma unroll
    for (int ms = 0; ms < 2; ++ms)
#pragma unroll
      for (int tr = 0; tr < 4; ++tr)
#pragma unroll
        for (int tc = 0; tc < 4; ++tc)
          acc[tr][tc] = __builtin_amdgcn_mfma_f32_16x16x32_bf16(a2[tr][ms], b2[tc][ms], acc[tr][tc], 0, 0, 0);
  }
  // epilogue2: HE = silu(. + eb2) -> HEt[ch][j] (transposed store, ~2-way banks)
#pragma unroll
  for (int tc = 0; tc < 4; ++tc) {
    float b2v = eb2[16 * tc + l15];
    int ch = 16 * tc + l15;
#pragma unroll
    for (int tr = 0; tr < 4; ++tr)
#pragma unroll
      for (int r = 0; r < 4; ++r) {
        int row = 64 * w + 16 * tr + quad * 4 + r;
        HEt[ch * 264 + row] = f2bf(silu_f(acc[tr][tc][r] + b2v));
      }
  }
  __syncthreads();                                               // s5

  // ================= P3: sem logits (fp32 semw via s_load) + softmaxes ========
  float4 sl = *reinterpret_cast<const float4*>(semb);
#pragma unroll 8
  for (int ch = 0; ch < 64; ++ch) {
    float he = bf2f(HEt[ch * 264 + tid]);          // 2-way bank, conflict-free
    const float4 swv = *reinterpret_cast<const float4*>(semw + ch * 4);  // uniform -> s_load
    sl.x += he * swv.x; sl.y += he * swv.y; sl.z += he * swv.z; sl.w += he * swv.w;
  }
  const float diag = (j == i) ? INFV : 0.0f;
  sl.x = ((sl.x > 0.f) ? sl.x : 0.2f * sl.x) - diag;
  sl.y = ((sl.y > 0.f) ? sl.y : 0.2f * sl.y) - diag;
  sl.z = ((sl.z > 0.f) ? sl.z : 0.2f * sl.z) - diag;
  sl.w = ((sl.w > 0.f) ? sl.w : 0.2f * sl.w) - diag;

  float4 lg = *reinterpret_cast<const float4*>(lgam);
  const float dni = dn + diag;
  // euclid logits <= 0: exp without max-subtraction safe (diag underflows to 0)
  float4 e_eu = make_float4(__expf(-dni * __expf(lg.x)), __expf(-dni * __expf(lg.y)),
                            __expf(-dni * __expf(lg.z)), __expf(-dni * __expf(lg.w)));

  // Round A: max(sl) batched with sum(e_eu)
  float4 M, Se;
  {
    float4 m4 = sl, s4 = e_eu;
#pragma unroll
    for (int off = 32; off >= 1; off >>= 1) {
      m4.x = fmaxf(m4.x, __shfl_xor(m4.x, off)); m4.y = fmaxf(m4.y, __shfl_xor(m4.y, off));
      m4.z = fmaxf(m4.z, __shfl_xor(m4.z, off)); m4.w = fmaxf(m4.w, __shfl_xor(m4.w, off));
      s4.x += __shfl_xor(s4.x, off); s4.y += __shfl_xor(s4.y, off);
      s4.z += __shfl_xor(s4.z, off); s4.w += __shfl_xor(s4.w, off);
    }
    if (lid == 0) { sc[w] = m4; sc[4 + w] = s4; }
    __syncthreads();
    float4 r0 = sc[0], r1 = sc[1], r2 = sc[2], r3 = sc[3];
    M = make_float4(fmaxf(fmaxf(r0.x, r1.x), fmaxf(r2.x, r3.x)),
                    fmaxf(fmaxf(r0.y, r1.y), fmaxf(r2.y, r3.y)),
                    fmaxf(fmaxf(r0.z, r1.z), fmaxf(r2.z, r3.z)),
                    fmaxf(fmaxf(r0.w, r1.w), fmaxf(r2.w, r3.w)));
    float4 s0 = sc[4], s1 = sc[5], s2 = sc[6], s3 = sc[7];
    Se = make_float4(s0.x + s1.x + s2.x + s3.x, s0.y + s1.y + s2.y + s3.y,
                     s0.z + s1.z + s2.z + s3.z, s0.w + s1.w + s2.w + s3.w);
    __syncthreads();
  }
  // Round B: sum(e_sem)
  float4 e_sem = make_float4(__expf(sl.x - M.x), __expf(sl.y - M.y),
                             __expf(sl.z - M.z), __expf(sl.w - M.w));
  float4 Ss;
  {
    float4 s4 = e_sem;
#pragma unroll
    for (int off = 32; off >= 1; off >>= 1) {
      s4.x += __shfl_xor(s4.x, off); s4.y += __shfl_xor(s4.y, off);
      s4.z += __shfl_xor(s4.z, off); s4.w += __shfl_xor(s4.w, off);
    }
    if (lid == 0) sc[w] = s4;
    __syncthreads();
    float4 s0 = sc[0], s1 = sc[1], s2 = sc[2], s3 = sc[3];
    Ss = make_float4(s0.x + s1.x + s2.x + s3.x, s0.y + s1.y + s2.y + s3.y,
                     s0.z + s1.z + s2.z + s3.z, s0.w + s1.w + s2.w + s3.w);
    __syncthreads();
  }
  // Round C: product softmax (p in [0,1] -> exp safe)
  float4 p = make_float4((e_eu.x * rcp_f(Se.x)) * (e_sem.x * rcp_f(Ss.x)),
                         (e_eu.y * rcp_f(Se.y)) * (e_sem.y * rcp_f(Ss.y)),
                         (e_eu.z * rcp_f(Se.z)) * (e_sem.z * rcp_f(Ss.z)),
                         (e_eu.w * rcp_f(Se.w)) * (e_sem.w * rcp_f(Ss.w)));
  float4 ep = make_float4(__expf(p.x), __expf(p.y), __expf(p.z), __expf(p.w));
  float4 catt;
  {
    float4 s4 = ep;
#pragma unroll
    for (int off = 32; off >= 1; off >>= 1) {
      s4.x += __shfl_xor(s4.x, off); s4.y += __shfl_xor(s4.y, off);
      s4.z += __shfl_xor(s4.z, off); s4.w += __shfl_xor(s4.w, off);
    }
    if (lid == 0) sc[w] = s4;
    __syncthreads();
    float4 s0 = sc[0], s1 = sc[1], s2 = sc[2], s3 = sc[3];
    float4 Sp = make_float4(s0.x + s1.x + s2.x + s3.x, s0.y + s1.y + s2.y + s3.y,
                            s0.z + s1.z + s2.z + s3.z, s0.w + s1.w + s2.w + s3.w);
    catt = make_float4(ep.x * rcp_f(Sp.x), ep.y * rcp_f(Sp.y),
                       ep.z * rcp_f(Sp.z), ep.w * rcp_f(Sp.w));
    __syncthreads();   // Bt may now overwrite E2u (all sc/W2 phases done)
  }

  // Bt[n][j] from registers: cols 0-3 = catt[h], 4+3h+d = catt[h]*unit[d]
  {
    float cv[4] = {catt.x, catt.y, catt.z, catt.w};
    float uv[3] = {ux, uy, uz};
#pragma unroll
    for (int hd = 0; hd < 4; ++hd) {
      Bt[hd * 264 + j] = f2bf(cv[hd]);
#pragma unroll
      for (int d = 0; d < 3; ++d)
        Bt[(4 + hd * 3 + d) * 264 + j] = f2bf(cv[hd] * uv[d]);
    }
  }
  __syncthreads();                                               // s6

  // ========== P4: one MFMA GEMM: D[64ch x 16] = HE^T @ Bt^T, K=256 ==========
  {
    f32x4 a4 = (f32x4){0.f, 0.f, 0.f, 0.f};
#pragma unroll
    for (int ks = 0; ks < 8; ++ks) {
      bf16x8 av = *reinterpret_cast<const bf16x8*>(&HEt[(16 * w + l15) * 264 + ks * 32 + quad * 8]);
      bf16x8 bv = *reinterpret_cast<const bf16x8*>(&Bt[l15 * 264 + ks * 32 + quad * 8]);
      a4 = __builtin_amdgcn_mfma_f32_16x16x32_bf16(av, bv, a4, 0, 0, 0);
    }
    const float inv = 1.0f / 256.0f;
#pragma unroll
    for (int r = 0; r < 4; ++r) {
      int ch = 16 * w + quad * 4 + r;
      if (l15 < 4) hag_l[ch * 4 + l15] = a4[r];
      else         comps[ch * 12 + (l15 - 4)] = a4[r] * inv;
    }
  }
  __syncthreads();                                               // s7

  // cn + delta_v (fp32 vmix), one reduction round
  float dvx, dvy, dvz;
  {
    int chh = tid >> 2, hh = tid & 3;
    float cx = comps[chh * 12 + hh * 3 + 0];
    float cy = comps[chh * 12 + hh * 3 + 1];
    float cz = comps[chh * 12 + hh * 3 + 2];
    cn_l[tid] = cx * cx + cy * cy + cz * cz;
    float vmw = vmix[tid];
    float px = vmw * cx, py = vmw * cy, pz = vmw * cz;
#pragma unroll
    for (int off = 32; off >= 1; off >>= 1) {
      px += __shfl_xor(px, off); py += __shfl_xor(py, off); pz += __shfl_xor(pz, off);
    }
    if (lid == 0) sc[w] = make_float4(px, py, pz, 0.f);
    __syncthreads();   // also publishes cn_l/hag_l for P5
    float4 r0 = sc[0], r1 = sc[1], r2 = sc[2], r3 = sc[3];
    dvx = r0.x + r1.x + r2.x + r3.x;
    dvy = r0.y + r1.y + r2.y + r3.y;
    dvz = r0.z + r1.z + r2.z + r3.z;
    __syncthreads();   // HEt fully consumed -> tail scratch may overwrite THu
  }

  // ================= P5: tail MLPs, strip-parallel (wave = strip) =================
  const int k = tid & 63;
  // post1: 256 -> 64
  {
    float a = 0.f;
    for (int m2 = 0; m2 < 64; ++m2) {
      int m = w * 64 + m2;
      a += cn_l[m] * pw1[m * 64 + k];
    }
    tmp[tid] = a;
  }
  __syncthreads();
  if (tid < 64) m1s[tid] = silu_f(pb1[tid] + tmp[tid] + tmp[64 + tid] + tmp[128 + tid] + tmp[192 + tid]);
  __syncthreads();
  // post2: 64 -> 64 ; stage h_agg into nin
  {
    float a = 0.f;
#pragma unroll
    for (int m2 = 0; m2 < 16; ++m2) {
      int m = w * 16 + m2;
      a += m1s[m] * pw2[m * 64 + k];
    }
    float hgv = hag_l[tid];
    __syncthreads();
    tmp[tid] = a;
    nin[64 + tid] = hgv;
  }
  __syncthreads();
  if (tid < 64) {
    nin[tid] = h[(size_t)bi * 64 + tid];
    nin[320 + tid] = silu_f(pb2[tid] + tmp[tid] + tmp[64 + tid] + tmp[128 + tid] + tmp[192 + tid]);
  }
  __syncthreads();
  // node1: 384 -> 64
  {
    float a = 0.f;
    for (int m2 = 0; m2 < 96; ++m2) {
      int m = w * 96 + m2;
      a += nin[m] * nw1[m * 64 + k];
    }
    __syncthreads();
    tmp[tid] = a;
  }
  __syncthreads();
  if (tid < 64) m1s[tid] = silu_f(nb1[tid] + tmp[tid] + tmp[64 + tid] + tmp[128 + tid] + tmp[192 + tid]);
  __syncthreads();
  // node2: 64 -> 64, residual
  {
    float a = 0.f;
#pragma unroll
    for (int m2 = 0; m2 < 16; ++m2) {
      int m = w * 16 + m2;
      a += m1s[m] * nw2[m * 64 + k];
    }
    __syncthreads();
    tmp[tid] = a;
  }
  __syncthreads();
  if (tid < 64) {
    float hn = h[(size_t)bi * 64 + tid] +
               silu_f(nb2[tid] + tmp[tid] + tmp[64 + tid] + tmp[128 + tid] + tmp[192 + tid]);
    out[(size_t)bi * 64 + tid] = hn;
    hnw[tid] = hn;
  }
  __syncthreads();
  // vel: 64 -> 64 -> scalar, then x/v outputs
  {
    float a = 0.f;
#pragma unroll
    for (int m2 = 0; m2 < 16; ++m2) {
      int m = w * 16 + m2;
      a += hnw[m] * vw1[m * 64 + k];
    }
    __syncthreads();
    tmp[tid] = a;
  }
  __syncthreads();
  if (tid < 64) {
    float vh = silu_f(vb1[tid] + tmp[tid] + tmp[64 + tid] + tmp[128 + tid] + tmp[192 + tid]) * vw2[tid];
#pragma unroll
    for (int off = 32; off >= 1; off >>= 1) vh += __shfl_xor(vh, off);
    if (tid == 0) {
      float dvv[3] = {dvx, dvy, dvz};
#pragma unroll
      for (int d = 0; d < 3; ++d) {
        float vn = dvv[d] + vh * v[bi * 3 + d];
        out[32768 + bi * 3 + d] = x[bi * 3 + d] + vn;
        out[34304 + bi * 3 + d] = vn;
      }
    }
  }
}

extern "C" void kernel_launch(void* const* d_in, const int* in_sizes, int n_in,
                              void* d_out, int out_size, void* d_ws, size_t ws_size,
                              hipStream_t stream) {
  const float* h    = (const float*)d_in[0];
  const float* x    = (const float*)d_in[1];
  const float* v    = (const float*)d_in[2];
  const float* ew1  = (const float*)d_in[3];
  const float* eb1  = (const float*)d_in[4];
  const float* ew2  = (const float*)d_in[5];
  const float* eb2  = (const float*)d_in[6];
  const float* semw = (const float*)d_in[7];
  const float* semb = (const float*)d_in[8];
  const float* pw1  = (const float*)d_in[9];
  const float* pb1  = (const float*)d_in[10];
  const float* pw2  = (const float*)d_in[11];
  const float* pb2  = (const float*)d_in[12];
  const float* nw1  = (const float*)d_in[13];
  const float* nb1  = (const float*)d_in[14];
  const float* nw2  = (const float*)d_in[15];
  const float* nb2  = (const float*)d_in[16];
  const float* vw1  = (const float*)d_in[17];
  const float* vb1  = (const float*)d_in[18];
  const float* vw2  = (const float*)d_in[19];
  const float* vmix = (const float*)d_in[20];
  const float* lgam = (const float*)d_in[21];
  float* out = (float*)d_out;

  k_all<<<512, 256, 0, stream>>>(h, x, v, ew1, eb1, ew2, eb2, semw, semb,
                                 pw1, pb1, pw2, pb2, nw1, nb1, nw2, nb2,
                                 vw1, vb1, vw2, vmix, lgam, out);
}